// Round 9
// baseline (14501.151 us; speedup 1.0000x reference)
//
#include <hip/hip_runtime.h>
#include <stdint.h>

#define Bsz 1024
#define Hsz 1024
#define Psteps 96
#define Ssamp 100
#define COVn 31

typedef __attribute__((ext_vector_type(8))) short short8;
typedef __attribute__((ext_vector_type(4))) float f32x4;

__device__ inline unsigned short f2bf(float f) {
    union { float f; unsigned u; } v; v.f = f;
    unsigned r = v.u + 0x7FFFu + ((v.u >> 16) & 1u);
    return (unsigned short)(r >> 16);
}

__device__ inline float sigm(float x) { return 1.f / (1.f + __expf(-x)); }
__device__ inline float tanh_f(float x) { return 2.f / (1.f + __expf(-2.f * x)) - 1.f; }
__device__ inline float softplusf(float x) {
    return fmaxf(x, 0.f) + log1pf(__expf(-fabsf(x)));
}

__device__ inline void gld16(const unsigned short* g, unsigned short* l) {
    auto gp = (const __attribute__((address_space(1))) unsigned int*)(const unsigned int*)g;
    auto lp = (__attribute__((address_space(3))) unsigned int*)(unsigned int*)l;
    __builtin_amdgcn_global_load_lds(gp, lp, 16, 0, 0);
}

// ---------------- prep kernels ----------------
// W0cat[4096][1088]: cols 0..31 = Wih0, 32..63 = 0, 64..1087 = Whh0 (gate rows interleaved g^=4h+g)
// W1cat[4096][2048]: cols 0..1023 = Wih1, 1024..2047 = Whh1
__global__ void prep_weights(const float* __restrict__ Wih0, const float* __restrict__ Whh0,
                             const float* __restrict__ Wih1, const float* __restrict__ Whh1,
                             const float* __restrict__ bih0, const float* __restrict__ bhh0,
                             const float* __restrict__ bih1, const float* __restrict__ bhh1,
                             unsigned short* __restrict__ W0cat, unsigned short* __restrict__ W1cat,
                             float* __restrict__ bias0, float* __restrict__ bias1) {
    const size_t N0 = (size_t)4096 * 1088;
    const size_t N1 = (size_t)4096 * 2048;
    const size_t total = N0 + N1 + 8192;
    for (size_t e = (size_t)blockIdx.x * 256 + threadIdx.x; e < total; e += (size_t)gridDim.x * 256) {
        if (e < N0) {
            int gh = (int)(e / 1088), col = (int)(e % 1088);
            int src = ((gh & 3) << 10) + (gh >> 2);
            float v;
            if (col < 32) v = Wih0[(size_t)src * 32 + col];
            else if (col < 64) v = 0.f;
            else v = Whh0[(size_t)src * 1024 + (col - 64)];
            W0cat[e] = f2bf(v);
        } else if (e < N0 + N1) {
            size_t m = e - N0;
            int gh = (int)(m >> 11), col = (int)(m & 2047);
            int src = ((gh & 3) << 10) + (gh >> 2);
            float v = (col < 1024) ? Wih1[(size_t)src * 1024 + col]
                                   : Whh1[(size_t)src * 1024 + (col - 1024)];
            W1cat[m] = f2bf(v);
        } else {
            size_t m = e - N0 - N1;             // 0..8191
            int which = (int)(m >> 12);
            int gh = (int)(m & 4095);
            int src = ((gh & 3) << 10) + (gh >> 2);
            if (which == 0) bias0[gh] = bih0[src] + bhh0[src];
            else            bias1[gh] = bih1[src] + bhh1[src];
        }
    }
}

// h stored [slot][B][H] bf16; slot 1 = initial (t=0 reads slot (0&1)^1 = 1).
// c stored [H][B] f32. Flags zeroed every call (graph-replay safe).
__global__ void prep_state(const float* __restrict__ hinit, const float* __restrict__ cinit,
                           unsigned short* __restrict__ hb0, unsigned short* __restrict__ hb1,
                           float* __restrict__ c0, float* __restrict__ c1,
                           int* __restrict__ flags, int nflags) {
    const size_t NM = (size_t)1024 * 1024;
    const size_t total = 4 * NM + (size_t)nflags;
    for (size_t e = (size_t)blockIdx.x * 256 + threadIdx.x; e < total; e += (size_t)gridDim.x * 256) {
        if (e < NM) {
            hb0[NM + e] = f2bf(hinit[e]);                  // slot 1
        } else if (e < 2 * NM) {
            hb1[NM + (e - NM)] = f2bf(hinit[e]);           // slot 1
        } else if (e < 3 * NM) {
            size_t j = e - 2 * NM; int h = (int)(j >> 10), b = (int)(j & 1023);
            c0[j] = cinit[(size_t)b * 1024 + h];
        } else if (e < 4 * NM) {
            size_t j = e - 3 * NM; int h = (int)(j >> 10), b = (int)(j & 1023);
            c1[j] = cinit[NM + (size_t)b * 1024 + h];
        } else {
            flags[e - 4 * NM] = 0;
        }
    }
}

// ---------------- persistent LSTM kernel ----------------
// Same GEMM body as the round-4 passing kernel: tile 128(M)x64(N), BK=64,
// 512 blocks = 2/CU co-resident, 4 waves (2x2), wave tile 64x32, acc[4][2],
// LDS 48KB (A dbuf 2x16K @0/16K, B dbuf 2x8K @32K/40K), XOR-swizzled staging
// via global_load_lds (plain cached — NT was a measured regression).
// Cross-block sync: per-(t, n_tile) flags, ONE release fetch_add per block
// (after __syncthreads), consumer spins relaxed + final acquire load +
// __syncthreads. All data moves are plain cached loads/stores; the
// release/acquire pair provides the cross-XCD visibility (documented model).
__global__ __launch_bounds__(256, 2) void lstm_persist(
        const float* __restrict__ cov, const float* __restrict__ initv,
        const float* __restrict__ noise, const float* __restrict__ bproj,
        const float* __restrict__ wproj,
        const unsigned short* __restrict__ W0, const unsigned short* __restrict__ W1,
        const float* __restrict__ bias0, const float* __restrict__ bias1,
        unsigned short* __restrict__ h0buf, unsigned short* __restrict__ h1buf,
        float* __restrict__ c0, float* __restrict__ c1,
        float* __restrict__ pPart,            // [2][32][1024][2] f32
        int* __restrict__ h0Flag, int* __restrict__ pbFlag,   // [96][16]
        float* __restrict__ outParams) {
    __shared__ __align__(16) char smem[49152];
    const int tid = threadIdx.x;
    const int m_tile = blockIdx.x & 31;      // %8 -> XCD: A slice affinity
    const int n_tile = blockIdx.x >> 5;      // 0..15
    const int m0 = m_tile * 128;
    const int hc0 = m_tile * 32;
    const int b0 = n_tile * 64;
    const int lane = tid & 63;
    const int wid = tid >> 6;
    const int wm = wid >> 1, wn = wid & 1;
    const size_t HB = (size_t)Bsz * Hsz;

    f32x4 acc[4][2];

    auto stageA = [&](const unsigned short* W, int stride, int k0, int bufsel) {
        unsigned short* Ab = (unsigned short*)(smem + bufsel * 16384);
        #pragma unroll
        for (int i = 0; i < 4; ++i) {
            int c = i * 256 + tid;
            int row = c >> 3, s = c & 7;
            int col = ((s ^ (row & 7)) << 3) + k0;
            gld16(W + (size_t)(m0 + row) * stride + col, Ab + c * 8);
        }
    };
    auto stageB = [&](const unsigned short* hsrc, int k0, int bufsel) {
        unsigned short* Bb = (unsigned short*)(smem + 32768 + bufsel * 8192);
        #pragma unroll
        for (int i = 0; i < 2; ++i) {
            int c = i * 256 + tid;
            int row = c >> 3, s = c & 7;
            int col = ((s ^ (row & 7)) << 3) + k0;
            gld16(hsrc + (size_t)(b0 + row) * 1024 + col, Bb + c * 8);
        }
    };
    auto computeIter = [&](int bufsel) {
        const char* Abuf = smem + bufsel * 16384;
        const char* Bbuf = smem + 32768 + bufsel * 8192;
        __builtin_amdgcn_s_setprio(1);
        #pragma unroll
        for (int kh = 0; kh < 2; ++kh) {
            short8 af[4], bq[2];
            #pragma unroll
            for (int mf = 0; mf < 4; ++mf) {
                int row = wm * 64 + mf * 16 + (lane & 15);
                int slot = (kh * 4 + (lane >> 4)) ^ (row & 7);
                af[mf] = *(const short8*)(Abuf + row * 128 + slot * 16);
            }
            #pragma unroll
            for (int nf = 0; nf < 2; ++nf) {
                int row = wn * 32 + nf * 16 + (lane & 15);
                int slot = (kh * 4 + (lane >> 4)) ^ (row & 7);
                bq[nf] = *(const short8*)(Bbuf + row * 128 + slot * 16);
            }
            #pragma unroll
            for (int mf = 0; mf < 4; ++mf)
                #pragma unroll
                for (int nf = 0; nf < 2; ++nf)
                    acc[mf][nf] = __builtin_amdgcn_mfma_f32_16x16x32_bf16(af[mf], bq[nf], acc[mf][nf], 0, 0, 0);
        }
        __builtin_amdgcn_s_setprio(0);
    };
    auto zeroAcc = [&]() {
        #pragma unroll
        for (int i = 0; i < 4; ++i)
            #pragma unroll
            for (int j = 0; j < 2; ++j) acc[i][j] = (f32x4){0.f, 0.f, 0.f, 0.f};
    };
    auto waitFlag = [&](int* f) {
        if (tid == 0) {
            while (__hip_atomic_load(f, __ATOMIC_RELAXED, __HIP_MEMORY_SCOPE_AGENT) < 32)
                __builtin_amdgcn_s_sleep(8);
            (void)__hip_atomic_load(f, __ATOMIC_ACQUIRE, __HIP_MEMORY_SCOPE_AGENT);  // inv L1/L2
        }
        __syncthreads();
    };
    auto signalFlag = [&](int* f) {
        __syncthreads();                      // all stores drained (vmcnt) + block-wide order
        if (tid == 0)
            __hip_atomic_fetch_add(f, 1, __ATOMIC_RELEASE, __HIP_MEMORY_SCOPE_AGENT);  // wb L2
    };

    for (int t = 0; t < Psteps; ++t) {
        const int ws = t & 1;
        const unsigned short* h0r = h0buf + (size_t)(ws ^ 1) * HB;
        unsigned short*       h0w = h0buf + (size_t)ws * HB;
        const unsigned short* h1r = h1buf + (size_t)(ws ^ 1) * HB;
        unsigned short*       h1w = h1buf + (size_t)ws * HB;
        const float* pRead = pPart + (size_t)(ws ^ 1) * 65536;
        float*      pWrite = pPart + (size_t)ws * 65536;

        // ================= CELL 0 =================
        // h-part first (16 iters, depends only on h0(t-1) — already synced last step)
        zeroAcc();
        stageA(W0, 1088, 64, 0);
        stageB(h0r, 0, 0);
        __syncthreads();
        for (int j = 0; j < 16; ++j) {
            if (j < 15) { stageA(W0, 1088, 64 + (j + 1) * 64, (j + 1) & 1); stageB(h0r, (j + 1) * 64, (j + 1) & 1); }
            else        { stageA(W0, 1088, 0, 0); }   // prefetch x-part A (cols 0..63) into buf0
            computeIter(j & 1);
            __syncthreads();
        }
        // x-part: needs params(t-1) from all 32 cell1 blocks of this n-slice
        {
            float* pj   = (float*)(smem + 40960);     // B buf1 (idle after iter 15)
            float* curF = (float*)(smem + 41984);
            if (t > 0) {
                waitFlag(&pbFlag[(t - 1) * 16 + n_tile]);
                if (tid < 128) {
                    int bl = tid >> 1, jj = tid & 1;
                    float s = bproj[jj];
                    #pragma unroll
                    for (int m = 0; m < 32; ++m)
                        s += pRead[(size_t)((m << 10) + b0 + bl) * 2 + jj];
                    pj[tid] = s;
                    if (m_tile == 0)
                        outParams[((size_t)(b0 + bl) * Psteps + (t - 1)) * 2 + jj] = s;
                }
                __syncthreads();
            }
            if (tid < 64) {
                float cu;
                if (t == 0) {
                    cu = initv[b0 + tid];
                } else {
                    float p0 = pj[tid * 2 + 0], p1 = pj[tid * 2 + 1];
                    cu = p0 + (softplusf(p1) + 1e-6f) * noise[(size_t)(t - 1) * (Ssamp * Bsz) + b0 + tid];
                }
                curF[tid] = cu;
            }
            __syncthreads();
            // X tile into B buf0 (swizzled): data cols 0..31 = [cur, cov0..30], 32..63 = 0
            #pragma unroll
            for (int i = 0; i < 2; ++i) {
                int c = i * 256 + tid;
                int row = c >> 3, s = c & 7;
                int ts = s ^ (row & 7);
                short8 v;
                if (ts < 4) {
                    const float* cr = cov + ((size_t)(b0 + row) * Psteps + t) * COVn;
                    #pragma unroll
                    for (int e = 0; e < 8; ++e) {
                        int col = ts * 8 + e;
                        float x = (col == 0) ? curF[row] : cr[col - 1];
                        v[e] = (short)f2bf(x);
                    }
                } else {
                    v = (short8){0, 0, 0, 0, 0, 0, 0, 0};
                }
                *(short8*)(smem + 32768 + c * 16) = v;
            }
            __syncthreads();
            computeIter(0);
            __syncthreads();
        }
        // epilogue cell0: nonlinearity, c0 update, h0 write
        {
            unsigned short* Ht = (unsigned short*)smem;   // A buf0 region (free now)
            #pragma unroll
            for (int mf = 0; mf < 4; ++mf) {
                int hl = wm * 16 + mf * 4 + (lane >> 4);
                int h = hc0 + hl;
                f32x4 bs = *(const f32x4*)&bias0[h * 4];
                #pragma unroll
                for (int nf = 0; nf < 2; ++nf) {
                    int bl = wn * 32 + nf * 16 + (lane & 15);
                    f32x4 v = acc[mf][nf];
                    float gi = sigm(v.x + bs.x);
                    float gf = sigm(v.y + bs.y);
                    float gg = tanh_f(v.z + bs.z);
                    float go = sigm(v.w + bs.w);
                    size_t ci = (size_t)h * Bsz + b0 + bl;
                    float cn = gf * c0[ci] + gi * gg;
                    c0[ci] = cn;
                    Ht[bl * 40 + hl] = f2bf(go * tanh_f(cn));
                }
            }
            __syncthreads();
            if (tid < 128) {
                int row = tid >> 1, hf = tid & 1;
                short8 v0 = *(const short8*)&Ht[row * 40 + hf * 16];
                short8 v1 = *(const short8*)&Ht[row * 40 + hf * 16 + 8];
                *(short8*)&h0w[(size_t)(b0 + row) * Hsz + hc0 + hf * 16] = v0;
                *(short8*)&h0w[(size_t)(b0 + row) * Hsz + hc0 + hf * 16 + 8] = v1;
            }
            signalFlag(&h0Flag[t * 16 + n_tile]);
        }

        // ================= CELL 1 =================
        // phase A: h1(t-1) half (16 iters, no wait needed)
        zeroAcc();
        stageA(W1, 2048, 1024, 0);
        stageB(h1r, 0, 0);
        __syncthreads();
        for (int j = 0; j < 16; ++j) {
            if (j < 15) { stageA(W1, 2048, 1024 + (j + 1) * 64, (j + 1) & 1); stageB(h1r, (j + 1) * 64, (j + 1) & 1); }
            else        { stageA(W1, 2048, 0, 0); }   // prefetch phase-B A (cols 0..63) into buf0
            computeIter(j & 1);
            __syncthreads();
        }
        // phase B: h0(t) half — wait for all cell0 blocks of this n-slice
        waitFlag(&h0Flag[t * 16 + n_tile]);
        stageB(h0w, 0, 0);
        __syncthreads();
        for (int j = 16; j < 32; ++j) {
            if (j < 31) { stageA(W1, 2048, (j - 15) * 64, (j + 1) & 1); stageB(h0w, (j - 15) * 64, (j + 1) & 1); }
            computeIter(j & 1);
            __syncthreads();
        }
        // epilogue cell1: nonlinearity, c1, h1 write, projection partials
        {
            unsigned short* Ht = (unsigned short*)smem;        // A buf0
            float* part = (float*)(smem + 16384);              // A buf1
            float pp[2][2] = {{0.f, 0.f}, {0.f, 0.f}};
            #pragma unroll
            for (int mf = 0; mf < 4; ++mf) {
                int hl = wm * 16 + mf * 4 + (lane >> 4);
                int h = hc0 + hl;
                f32x4 bs = *(const f32x4*)&bias1[h * 4];
                #pragma unroll
                for (int nf = 0; nf < 2; ++nf) {
                    int bl = wn * 32 + nf * 16 + (lane & 15);
                    f32x4 v = acc[mf][nf];
                    float gi = sigm(v.x + bs.x);
                    float gf = sigm(v.y + bs.y);
                    float gg = tanh_f(v.z + bs.z);
                    float go = sigm(v.w + bs.w);
                    size_t ci = (size_t)h * Bsz + b0 + bl;
                    float cn = gf * c1[ci] + gi * gg;
                    c1[ci] = cn;
                    float hn = go * tanh_f(cn);
                    Ht[bl * 40 + hl] = f2bf(hn);
                    pp[nf][0] += hn * wproj[h];
                    pp[nf][1] += hn * wproj[Hsz + h];
                }
            }
            #pragma unroll
            for (int nf = 0; nf < 2; ++nf)
                #pragma unroll
                for (int j = 0; j < 2; ++j) {
                    float v = pp[nf][j];
                    v += __shfl_xor(v, 16, 64);
                    v += __shfl_xor(v, 32, 64);
                    if (lane < 16)
                        part[((wm * 64) + wn * 32 + nf * 16 + lane) * 2 + j] = v;
                }
            __syncthreads();
            if (tid < 128) {
                int row = tid >> 1, hf = tid & 1;
                short8 v0 = *(const short8*)&Ht[row * 40 + hf * 16];
                short8 v1 = *(const short8*)&Ht[row * 40 + hf * 16 + 8];
                *(short8*)&h1w[(size_t)(b0 + row) * Hsz + hc0 + hf * 16] = v0;
                *(short8*)&h1w[(size_t)(b0 + row) * Hsz + hc0 + hf * 16 + 8] = v1;
                int bl = row, jj = hf;
                pWrite[(size_t)((m_tile << 10) + b0 + bl) * 2 + jj] =
                    part[bl * 2 + jj] + part[(64 + bl) * 2 + jj];
            }
            signalFlag(&pbFlag[t * 16 + n_tile]);
        }
    }
}

// ---------------- tail: params[t=95] + mu/sigma table ----------------
__global__ void tail_params(const float* __restrict__ pSlot, const float* __restrict__ bproj,
                            float* __restrict__ dout, float* __restrict__ musig) {
    int idx = blockIdx.x * 256 + threadIdx.x;
    if (idx >= Bsz * Psteps) return;
    int b = idx / Psteps, t = idx % Psteps;
    float p0, p1;
    if (t == Psteps - 1) {
        p0 = bproj[0]; p1 = bproj[1];
        #pragma unroll 8
        for (int m = 0; m < 32; ++m) {
            p0 += pSlot[(size_t)((m << 10) + b) * 2 + 0];
            p1 += pSlot[(size_t)((m << 10) + b) * 2 + 1];
        }
        dout[(size_t)idx * 2 + 0] = p0;
        dout[(size_t)idx * 2 + 1] = p1;
    } else {
        p0 = dout[(size_t)idx * 2 + 0];
        p1 = dout[(size_t)idx * 2 + 1];
    }
    musig[(size_t)idx * 2 + 0] = p0;
    musig[(size_t)idx * 2 + 1] = softplusf(p1) + 1e-6f;
}

// ---------------- sample generation (out layout (S,B,P)) ----------------
__global__ __launch_bounds__(256) void gen_samples(const float* __restrict__ noise,
                                                   const float* __restrict__ musig,
                                                   float* __restrict__ outS) {
    __shared__ float tile[16][97];
    int s = blockIdx.x >> 6;
    int b0 = (blockIdx.x & 63) << 4;
    int tid = threadIdx.x;
    for (int e = tid; e < Psteps * 16; e += 256) {
        int tt = e >> 4, b = e & 15;
        tile[b][tt] = noise[((size_t)tt * Ssamp + s) * Bsz + b0 + b];
    }
    __syncthreads();
    int b = tid >> 4, t0 = (tid & 15) * 6;
    const float* ms = musig + ((size_t)(b0 + b) * Psteps + t0) * 2;
    float* op = outS + ((size_t)s * Bsz + b0 + b) * Psteps + t0;
    #pragma unroll
    for (int k = 0; k < 6; ++k) {
        op[k] = ms[k * 2] + ms[k * 2 + 1] * tile[b][t0 + k];
    }
}

// ---------------- host ----------------
extern "C" void kernel_launch(void* const* d_in, const int* in_sizes, int n_in,
                              void* d_out, int out_size, void* d_ws, size_t ws_size,
                              hipStream_t stream) {
    const float* cov   = (const float*)d_in[0];
    const float* initv = (const float*)d_in[1];
    const float* noise = (const float*)d_in[2];
    const float* hinit = (const float*)d_in[3];
    const float* cinit = (const float*)d_in[4];
    const float* Wih0  = (const float*)d_in[5];
    const float* Whh0  = (const float*)d_in[6];
    const float* bih0  = (const float*)d_in[7];
    const float* bhh0  = (const float*)d_in[8];
    const float* Wih1  = (const float*)d_in[9];
    const float* Whh1  = (const float*)d_in[10];
    const float* bih1  = (const float*)d_in[11];
    const float* bhh1  = (const float*)d_in[12];
    const float* wproj = (const float*)d_in[13];
    const float* bproj = (const float*)d_in[14];
    float* dout = (float*)d_out;

    uint8_t* p = (uint8_t*)d_ws;
    auto alloc = [&](size_t bytes) { void* r = (void*)p; p += (bytes + 255) & ~(size_t)255; return r; };
    unsigned short* W0cat = (unsigned short*)alloc((size_t)4096 * 1088 * 2);
    unsigned short* W1cat = (unsigned short*)alloc((size_t)4096 * 2048 * 2);
    float* bias0 = (float*)alloc(4096 * 4);
    float* bias1 = (float*)alloc(4096 * 4);
    unsigned short* hb0 = (unsigned short*)alloc((size_t)2 * 1024 * 1024 * 2);
    unsigned short* hb1 = (unsigned short*)alloc((size_t)2 * 1024 * 1024 * 2);
    float* c0 = (float*)alloc((size_t)1024 * 1024 * 4);
    float* c1 = (float*)alloc((size_t)1024 * 1024 * 4);
    float* pPart = (float*)alloc((size_t)2 * 32 * 1024 * 2 * 4);
    float* musig = (float*)alloc((size_t)1024 * 96 * 2 * 4);
    int* flags = (int*)alloc((size_t)2 * Psteps * 16 * 4);   // h0Flag | pbFlag
    int* h0Flag = flags;
    int* pbFlag = flags + Psteps * 16;
    const int nflags = 2 * Psteps * 16;

    prep_weights<<<2048, 256, 0, stream>>>(Wih0, Whh0, Wih1, Whh1, bih0, bhh0, bih1, bhh1,
                                           W0cat, W1cat, bias0, bias1);
    prep_state<<<2048, 256, 0, stream>>>(hinit, cinit, hb0, hb1, c0, c1, flags, nflags);

    lstm_persist<<<512, 256, 0, stream>>>(cov, initv, noise, bproj, wproj,
                                          W0cat, W1cat, bias0, bias1,
                                          hb0, hb1, c0, c1, pPart, h0Flag, pbFlag, dout);

    tail_params<<<384, 256, 0, stream>>>(pPart + (size_t)((Psteps - 1) & 1) * 65536, bproj, dout, musig);
    gen_samples<<<6400, 256, 0, stream>>>(noise, musig, dout + (size_t)Bsz * Psteps * 2);
}

// Round 10
// 4136.112 us; speedup vs baseline: 3.5060x; 3.5060x over previous
//
#include <hip/hip_runtime.h>
#include <stdint.h>

#define Bsz 1024
#define Hsz 1024
#define Psteps 96
#define Ssamp 100
#define COVn 31

typedef __attribute__((ext_vector_type(8))) short short8;
typedef __attribute__((ext_vector_type(4))) float f32x4;

__device__ inline unsigned short f2bf(float f) {
    union { float f; unsigned u; } v; v.f = f;
    unsigned r = v.u + 0x7FFFu + ((v.u >> 16) & 1u);
    return (unsigned short)(r >> 16);
}

__device__ inline float sigm(float x) { return 1.f / (1.f + __expf(-x)); }
__device__ inline float tanh_f(float x) { return 2.f / (1.f + __expf(-2.f * x)) - 1.f; }
__device__ inline float softplusf(float x) {
    return fmaxf(x, 0.f) + log1pf(__expf(-fabsf(x)));
}

__device__ inline void gld16(const unsigned short* g, unsigned short* l) {
    auto gp = (const __attribute__((address_space(1))) unsigned int*)(const unsigned int*)g;
    auto lp = (__attribute__((address_space(3))) unsigned int*)(unsigned int*)l;
    __builtin_amdgcn_global_load_lds(gp, lp, 16, 0, 0);
}

// stage a ROWSx64 bf16 tile into LDS, source-side XOR-swizzled.
// chunk c at byte c*16; c = row*8 + s; content of (row,s) = global slot (s ^ (row&7)).
// CH = chunks per thread (ROWS*8/256). Plain cached loads (NT was a measured regression).
template<int CH>
__device__ inline void stage_tile(const unsigned short* __restrict__ src, int rowStride,
                                  int row0, int k0, unsigned short* ldsBase, int tid) {
    #pragma unroll
    for (int i = 0; i < CH; ++i) {
        int c = i * 256 + tid;
        int row = c >> 3, s = c & 7;
        int col = ((s ^ (row & 7)) << 3) + k0;
        gld16(src + (size_t)(row0 + row) * rowStride + col, ldsBase + c * 8);
    }
}

// ---------------- prep kernels ----------------
// W0cat[4096][1088]: cols 0..31 = Wih0, 32..63 = 0, 64..1087 = Whh0 (gate rows interleaved g^=4h+g)
// W1cat[4096][2048]: cols 0..1023 = Wih1, 1024..2047 = Whh1
__global__ void prep_weights(const float* __restrict__ Wih0, const float* __restrict__ Whh0,
                             const float* __restrict__ Wih1, const float* __restrict__ Whh1,
                             const float* __restrict__ bih0, const float* __restrict__ bhh0,
                             const float* __restrict__ bih1, const float* __restrict__ bhh1,
                             unsigned short* __restrict__ W0cat, unsigned short* __restrict__ W1cat,
                             float* __restrict__ bias0, float* __restrict__ bias1) {
    const size_t N0 = (size_t)4096 * 1088;
    const size_t N1 = (size_t)4096 * 2048;
    const size_t total = N0 + N1 + 8192;
    for (size_t e = (size_t)blockIdx.x * 256 + threadIdx.x; e < total; e += (size_t)gridDim.x * 256) {
        if (e < N0) {
            int gh = (int)(e / 1088), col = (int)(e % 1088);
            int src = ((gh & 3) << 10) + (gh >> 2);
            float v;
            if (col < 32) v = Wih0[(size_t)src * 32 + col];
            else if (col < 64) v = 0.f;
            else v = Whh0[(size_t)src * 1024 + (col - 64)];
            W0cat[e] = f2bf(v);
        } else if (e < N0 + N1) {
            size_t m = e - N0;
            int gh = (int)(m >> 11), col = (int)(m & 2047);
            int src = ((gh & 3) << 10) + (gh >> 2);
            float v = (col < 1024) ? Wih1[(size_t)src * 1024 + col]
                                   : Whh1[(size_t)src * 1024 + (col - 1024)];
            W1cat[m] = f2bf(v);
        } else {
            size_t m = e - N0 - N1;             // 0..8191
            int which = (int)(m >> 12);
            int gh = (int)(m & 4095);
            int src = ((gh & 3) << 10) + (gh >> 2);
            if (which == 0) bias0[gh] = bih0[src] + bhh0[src];
            else            bias1[gh] = bih1[src] + bhh1[src];
        }
    }
}

__global__ void prep_state(const float* __restrict__ hinit, const float* __restrict__ cinit,
                           unsigned short* __restrict__ hb0, unsigned short* __restrict__ hb1,
                           float* __restrict__ c0, float* __restrict__ c1) {
    const size_t NM = (size_t)1024 * 1024;
    for (size_t e = (size_t)blockIdx.x * 256 + threadIdx.x; e < 4 * NM; e += (size_t)gridDim.x * 256) {
        if (e < NM) {
            hb0[e] = f2bf(hinit[e]);                       // h stored [B][H] bf16
        } else if (e < 2 * NM) {
            hb1[e - NM] = f2bf(hinit[e]);
        } else if (e < 3 * NM) {
            size_t j = e - 2 * NM; int h = (int)(j >> 10), b = (int)(j & 1023);
            c0[j] = cinit[(size_t)b * 1024 + h];           // c stored [H][B] f32
        } else {
            size_t j = e - 3 * NM; int h = (int)(j >> 10), b = (int)(j & 1023);
            c1[j] = cinit[NM + (size_t)b * 1024 + h];
        }
    }
}

// ---------------- LSTM step GEMM kernel ----------------
// gates^T = W_cat (M=4096, g^=4h+g interleaved) x input^T (N=1024 batch)
// tile 128(M)x64(N), BK=64, grid 32m x 16n = 512 blocks -> 2 blocks/CU.
// 4 waves as 2(M)x2(N); wave tile 64x32; acc[4][2].
// LDS 72KB: A tri-buf 3x16K @0/16K/32K, B tri-buf 3x8K @48K/56K/64K.
// Depth-2 pipeline (m201-validated): stage(it+2) -> compute(it) ->
// s_waitcnt vmcnt(6) [stage(it+2) stays IN FLIGHT across the barrier] ->
// s_barrier. Buffer distance audited: stage(it+2) vs compute(it) laggards
// differ mod 3; barrier(it-1) bounds wave lag to one phase.
template<int CELL>
__global__ __launch_bounds__(256, 2) void lstm_step(
        int t,
        const float* __restrict__ cov, const float* __restrict__ initv,
        const float* __restrict__ noise, const float* __restrict__ bproj,
        const float* __restrict__ wproj,
        const unsigned short* __restrict__ WA,   // W0cat or W1cat
        const float* __restrict__ biasH,
        const unsigned short* __restrict__ hA,   // cell1: h0_new (first K half)
        const unsigned short* __restrict__ hB,   // cell0: h0_prev; cell1: h1_prev
        unsigned short* __restrict__ hOut,
        float* __restrict__ cws,
        float* __restrict__ pbufPartial,         // [32 m][1024 b][2]
        float* __restrict__ outParams) {
    __shared__ __align__(16) char smem[73728];

    const int tid = threadIdx.x;
    const int m_tile = blockIdx.x & 31;          // xcd = blockIdx%8 = m_tile%8 -> A L2 affinity
    const int n_tile = blockIdx.x >> 5;          // 0..15
    const int m0 = m_tile * 128;                 // gate-row base
    const int hc0 = m_tile * 32;                 // h base (128 gates / 4)
    const int b0 = n_tile * 64;
    const int lane = tid & 63;
    const int wid = tid >> 6;
    const int wm = wid >> 1, wn = wid & 1;
    const int NIT = (CELL == 0) ? 17 : 32;

    auto stageIt = [&](int j) {
        int bsel = j % 3;
        unsigned short* Ab = (unsigned short*)(smem + bsel * 16384);
        unsigned short* Bb = (unsigned short*)(smem + 49152 + bsel * 8192);
        if (CELL == 0) {
            stage_tile<4>(WA, 1088, m0, j * 64, Ab, tid);
            if (j > 0) stage_tile<2>(hB, 1024, b0, (j - 1) * 64, Bb, tid);
        } else {
            stage_tile<4>(WA, 2048, m0, j * 64, Ab, tid);
            if (j < 16) stage_tile<2>(hA, 1024, b0, j * 64, Bb, tid);
            else        stage_tile<2>(hB, 1024, b0, (j - 16) * 64, Bb, tid);
        }
    };

    // ---------- prologue: issue stages 0,1; build X (cell0) ----------
    stageIt(0);
    stageIt(1);
    if (CELL == 0) {
        float* pj   = (float*)(smem + 65536);         // B-buf2 region: first staged at
        float* curF = (float*)(smem + 65536 + 512);   // loop iter 0 (after prologue sync)
        if (t > 0) {
            if (tid < 128) {
                int bl = tid >> 1, j = tid & 1;
                float s = bproj[j];
                #pragma unroll 8
                for (int m = 0; m < 32; ++m)
                    s += pbufPartial[(size_t)((m << 10) + b0 + bl) * 2 + j];
                pj[tid] = s;
                if (m_tile == 0)
                    outParams[((size_t)(b0 + bl) * Psteps + (t - 1)) * 2 + j] = s;
            }
        }
        __syncthreads();
        if (tid < 64) {
            float cu;
            if (t == 0) {
                cu = initv[b0 + tid];
            } else {
                float p0 = pj[tid * 2 + 0], p1 = pj[tid * 2 + 1];
                cu = p0 + (softplusf(p1) + 1e-6f) * noise[(size_t)(t - 1) * (Ssamp * Bsz) + b0 + tid];
            }
            curF[tid] = cu;
        }
        __syncthreads();
        // build X tile into B buffer 0 (64 rows x 64 cols, swizzled):
        // data cols 0..31 = [cur, cov0..30], cols 32..63 = 0
        #pragma unroll
        for (int i = 0; i < 2; ++i) {
            int c = i * 256 + tid;
            int row = c >> 3, s = c & 7;
            int ts = s ^ (row & 7);
            short8 v;
            if (ts < 4) {
                const float* cr = cov + ((size_t)(b0 + row) * Psteps + t) * COVn;
                #pragma unroll
                for (int e = 0; e < 8; ++e) {
                    int col = ts * 8 + e;
                    float x = (col == 0) ? curF[row] : cr[col - 1];
                    v[e] = (short)f2bf(x);
                }
            } else {
                v = (short8){0, 0, 0, 0, 0, 0, 0, 0};
            }
            *(short8*)(smem + 49152 + c * 16) = v;
        }
    }
    __syncthreads();   // stages 0,1 landed; X committed

    f32x4 acc[4][2];
    #pragma unroll
    for (int i = 0; i < 4; ++i)
        #pragma unroll
        for (int j = 0; j < 2; ++j) acc[i][j] = (f32x4){0.f, 0.f, 0.f, 0.f};

    // ---------- main loop: depth-2, counted vmcnt, raw barrier ----------
    for (int it = 0; it < NIT; ++it) {
        if (it + 2 < NIT) stageIt(it + 2);
        int bsel = it % 3;
        const char* Abuf = smem + bsel * 16384;
        const char* Bbuf = smem + 49152 + bsel * 8192;
        __builtin_amdgcn_s_setprio(1);
        #pragma unroll
        for (int kh = 0; kh < 2; ++kh) {
            short8 af[4], bq[2];
            #pragma unroll
            for (int mf = 0; mf < 4; ++mf) {
                int row = wm * 64 + mf * 16 + (lane & 15);
                int slot = (kh * 4 + (lane >> 4)) ^ (row & 7);
                af[mf] = *(const short8*)(Abuf + row * 128 + slot * 16);
            }
            #pragma unroll
            for (int nf = 0; nf < 2; ++nf) {
                int row = wn * 32 + nf * 16 + (lane & 15);
                int slot = (kh * 4 + (lane >> 4)) ^ (row & 7);
                bq[nf] = *(const short8*)(Bbuf + row * 128 + slot * 16);
            }
            #pragma unroll
            for (int mf = 0; mf < 4; ++mf)
                #pragma unroll
                for (int nf = 0; nf < 2; ++nf)
                    acc[mf][nf] = __builtin_amdgcn_mfma_f32_16x16x32_bf16(af[mf], bq[nf], acc[mf][nf], 0, 0, 0);
        }
        __builtin_amdgcn_s_setprio(0);
        if (it + 1 < NIT) {
            // need stage(it+1) retired; stage(it+2) (6 loads/wave) may stay in flight
            if (it + 2 < NIT) asm volatile("s_waitcnt vmcnt(6)" ::: "memory");
            else              asm volatile("s_waitcnt vmcnt(0)" ::: "memory");
            __builtin_amdgcn_s_barrier();
        }
    }
    __syncthreads();   // all waves done with LDS buffers before epilogue reuse

    // ---------- epilogue ----------
    unsigned short* Ht = (unsigned short*)smem;      // [64 b][40] bf16 (A-buf0)
    float* part = (float*)(smem + 16384);            // [2 wm][64 b][2 j] (A-buf1)
    float pp[2][2];
    if (CELL == 1) {
        #pragma unroll
        for (int nf = 0; nf < 2; ++nf) { pp[nf][0] = 0.f; pp[nf][1] = 0.f; }
    }
    #pragma unroll
    for (int mf = 0; mf < 4; ++mf) {
        int hl = wm * 16 + mf * 4 + (lane >> 4);
        int h = hc0 + hl;
        f32x4 bs = *(const f32x4*)&biasH[h * 4];
        #pragma unroll
        for (int nf = 0; nf < 2; ++nf) {
            int bl = wn * 32 + nf * 16 + (lane & 15);
            int b = b0 + bl;
            f32x4 v = acc[mf][nf];
            float gi = sigm(v.x + bs.x);
            float gf = sigm(v.y + bs.y);
            float gg = tanh_f(v.z + bs.z);
            float go = sigm(v.w + bs.w);
            size_t ci = (size_t)h * Bsz + b;
            float cn = gf * cws[ci] + gi * gg;
            cws[ci] = cn;
            float hn = go * tanh_f(cn);
            Ht[bl * 40 + hl] = f2bf(hn);
            if (CELL == 1) {
                pp[nf][0] += hn * wproj[h];
                pp[nf][1] += hn * wproj[Hsz + h];
            }
        }
    }
    if (CELL == 1) {
        #pragma unroll
        for (int nf = 0; nf < 2; ++nf)
            #pragma unroll
            for (int j = 0; j < 2; ++j) {
                float v = pp[nf][j];
                v += __shfl_xor(v, 16, 64);
                v += __shfl_xor(v, 32, 64);
                if (lane < 16)
                    part[((wm * 64) + wn * 32 + nf * 16 + lane) * 2 + j] = v;
            }
    }
    __syncthreads();
    if (tid < 128) {   // coalesced h write: 64 rows x 64B contiguous
        int row = tid >> 1, hf = tid & 1;
        short8 v0 = *(const short8*)&Ht[row * 40 + hf * 16];
        short8 v1 = *(const short8*)&Ht[row * 40 + hf * 16 + 8];
        *(short8*)&hOut[(size_t)(b0 + row) * Hsz + hc0 + hf * 16] = v0;
        *(short8*)&hOut[(size_t)(b0 + row) * Hsz + hc0 + hf * 16 + 8] = v1;
    }
    if (CELL == 1 && tid < 128) {
        int bl = tid >> 1, j = tid & 1;
        pbufPartial[((size_t)m_tile * 1024 + b0 + bl) * 2 + j] =
            part[bl * 2 + j] + part[(64 + bl) * 2 + j];
    }
}

// ---------------- tail: params[t=95] + mu/sigma table ----------------
__global__ void tail_params(const float* __restrict__ pPart, const float* __restrict__ bproj,
                            float* __restrict__ dout, float* __restrict__ musig) {
    int idx = blockIdx.x * 256 + threadIdx.x;
    if (idx >= Bsz * Psteps) return;
    int b = idx / Psteps, t = idx % Psteps;
    float p0, p1;
    if (t == Psteps - 1) {
        p0 = bproj[0]; p1 = bproj[1];
        #pragma unroll 8
        for (int m = 0; m < 32; ++m) {
            p0 += pPart[(size_t)((m << 10) + b) * 2 + 0];
            p1 += pPart[(size_t)((m << 10) + b) * 2 + 1];
        }
        dout[(size_t)idx * 2 + 0] = p0;
        dout[(size_t)idx * 2 + 1] = p1;
    } else {
        p0 = dout[(size_t)idx * 2 + 0];
        p1 = dout[(size_t)idx * 2 + 1];
    }
    musig[(size_t)idx * 2 + 0] = p0;
    musig[(size_t)idx * 2 + 1] = softplusf(p1) + 1e-6f;
}

// ---------------- sample generation (out layout (S,B,P)) ----------------
// grid = 100 s * 64 batch-chunks = 6400 blocks of (s, 16 batch)
__global__ __launch_bounds__(256) void gen_samples(const float* __restrict__ noise,
                                                   const float* __restrict__ musig,
                                                   float* __restrict__ outS) {
    __shared__ float tile[16][97];
    int s = blockIdx.x >> 6;
    int b0 = (blockIdx.x & 63) << 4;
    int tid = threadIdx.x;
    for (int e = tid; e < Psteps * 16; e += 256) {
        int tt = e >> 4, b = e & 15;
        tile[b][tt] = noise[((size_t)tt * Ssamp + s) * Bsz + b0 + b];
    }
    __syncthreads();
    int b = tid >> 4, t0 = (tid & 15) * 6;
    const float* ms = musig + ((size_t)(b0 + b) * Psteps + t0) * 2;
    float* op = outS + ((size_t)s * Bsz + b0 + b) * Psteps + t0;
    #pragma unroll
    for (int k = 0; k < 6; ++k) {
        op[k] = ms[k * 2] + ms[k * 2 + 1] * tile[b][t0 + k];
    }
}

// ---------------- host ----------------
extern "C" void kernel_launch(void* const* d_in, const int* in_sizes, int n_in,
                              void* d_out, int out_size, void* d_ws, size_t ws_size,
                              hipStream_t stream) {
    const float* cov   = (const float*)d_in[0];
    const float* initv = (const float*)d_in[1];
    const float* noise = (const float*)d_in[2];
    const float* hinit = (const float*)d_in[3];
    const float* cinit = (const float*)d_in[4];
    const float* Wih0  = (const float*)d_in[5];
    const float* Whh0  = (const float*)d_in[6];
    const float* bih0  = (const float*)d_in[7];
    const float* bhh0  = (const float*)d_in[8];
    const float* Wih1  = (const float*)d_in[9];
    const float* Whh1  = (const float*)d_in[10];
    const float* bih1  = (const float*)d_in[11];
    const float* bhh1  = (const float*)d_in[12];
    const float* wproj = (const float*)d_in[13];
    const float* bproj = (const float*)d_in[14];
    float* dout = (float*)d_out;

    uint8_t* p = (uint8_t*)d_ws;
    auto alloc = [&](size_t bytes) { void* r = (void*)p; p += (bytes + 255) & ~(size_t)255; return r; };
    unsigned short* W0cat = (unsigned short*)alloc((size_t)4096 * 1088 * 2);
    unsigned short* W1cat = (unsigned short*)alloc((size_t)4096 * 2048 * 2);
    float* bias0 = (float*)alloc(4096 * 4);
    float* bias1 = (float*)alloc(4096 * 4);
    unsigned short* hb0 = (unsigned short*)alloc((size_t)2 * 1024 * 1024 * 2 + 256);
    unsigned short* hb1 = (unsigned short*)alloc((size_t)2 * 1024 * 1024 * 2 + 256);
    float* c0 = (float*)alloc((size_t)1024 * 1024 * 4);
    float* c1 = (float*)alloc((size_t)1024 * 1024 * 4);
    float* pbufPartial = (float*)alloc((size_t)32 * 1024 * 2 * 4);
    float* musig = (float*)alloc((size_t)1024 * 96 * 2 * 4);

    prep_weights<<<2048, 256, 0, stream>>>(Wih0, Whh0, Wih1, Whh1, bih0, bhh0, bih1, bhh1,
                                           W0cat, W1cat, bias0, bias1);
    prep_state<<<2048, 256, 0, stream>>>(hinit, cinit, hb0, hb1, c0, c1);

    const size_t HB = (size_t)1024 * 1024;
    for (int t = 0; t < Psteps; ++t) {
        const unsigned short* h0p = hb0 + (size_t)(t & 1) * HB;
        unsigned short* h0n = hb0 + (size_t)((t + 1) & 1) * HB;
        const unsigned short* h1p = hb1 + (size_t)(t & 1) * HB;
        unsigned short* h1n = hb1 + (size_t)((t + 1) & 1) * HB;
        lstm_step<0><<<512, 256, 0, stream>>>(t, cov, initv, noise, bproj, wproj,
                                              W0cat, bias0, nullptr, h0p, h0n, c0,
                                              pbufPartial, dout);
        lstm_step<1><<<512, 256, 0, stream>>>(t, cov, initv, noise, bproj, wproj,
                                              W1cat, bias1, h0n, h1p, h1n, c1,
                                              pbufPartial, dout);
    }
    tail_params<<<384, 256, 0, stream>>>(pbufPartial, bproj, dout, musig);
    gen_samples<<<6400, 256, 0, stream>>>(noise, musig, dout + (size_t)Bsz * Psteps * 2);
}